// Round 10
// baseline (5570.546 us; speedup 1.0000x reference)
//
#include <hip/hip_runtime.h>
#include <math.h>

#define B_   256
#define E_   304
#define H_   304
#define T_   512
#define P_   68
#define PD   67      // decoder output positions
#define D_   61
#define NCB  16      // col-blocks per batch group
#define NBG  16      // batch groups
#define RB   16      // rows (batch) per block -- full MFMA M dim
#define CBH  19      // h-cols per block
#define GC   57      // gate-cols per block (3*19)
#define NSTEP (T_ + PD)
#define HW   152     // ull words per f32 row (304 floats)
#define BLK_ULL (RB * HW)   // 2432
#define LROW 328     // padded f16 row length (K 320 + pad)
#define LROWU 164    // u32 (f16-pair) words per row
#define NKS  10      // K-steps of 32 (K padded 304->320)
#define SLICE 304    // elements per exchange slice (16 rows x 19 cols)
#define SLICEP 320   // padded slice stride (u32)
#define RSTR 20      // red[] row stride (words); col*80B + g*16B -> 16B aligned
#define SC_LO 2048.0f
#define SC_INV 4.8828125e-4f   // 2^-11

typedef unsigned long long ull;
typedef _Float16 half8 __attribute__((ext_vector_type(8)));
typedef _Float16 half2v __attribute__((ext_vector_type(2)));
typedef float f32x4 __attribute__((ext_vector_type(4)));

// ---------------------------------------------------------------------------
// Persistent GRU via split-f16 MFMA + point-to-point dataflow h-exchange.
// Grid 256 blocks, 256 thr, 1 block/CU. XCD-local groups (L%8 swizzle).
// Block (cb,bg): rows r0=bg*16..+15, h-cols c0h=cb*19..+18.
// h exchanged as packed u32 (f16 hi | f16 lo'<<16, lo' = residual x 2048) in
// per-producer contiguous slices xbuf[parity][bg][cb][304]; producer drains
// stores (syncthreads) then sets flag[bg][cb] = s+1 (monotonic). Consumers'
// waves poll 4 flags each and unpack slices as they arrive (no global
// rendezvous, no RMW serialization; early slices overlap the last one).
// Causality: flag is stored only after producer's slice stores are ACKed
// (vmcnt 0 at the preceding __syncthreads), so flag-visible => data-visible.
// Per iter s: top-sync | stage x(s+1) | prefetch x(s+2) | consume h(s) slices
// | mid-sync | gh MFMA -> red1 | red-sync | gates -> pack h(s+1) slice store
// (+dec_outs) | drain-sync | tid0 flag=s+1 | gi(s+1) -> red0.
// ---------------------------------------------------------------------------
__global__ __launch_bounds__(256, 1) void gru_persist(
    const float* __restrict__ input,   // [B][T][E]
    const int*   __restrict__ target,  // [B][P]
    const float* __restrict__ emb,     // [D][E]
    const float* __restrict__ eWih, const float* __restrict__ eWhh,
    const float* __restrict__ ebih, const float* __restrict__ ebhh,
    const float* __restrict__ dWih, const float* __restrict__ dWhh,
    const float* __restrict__ dbih, const float* __restrict__ dbhh,
    unsigned* xbuf,                    // [2][NBG][NCB][SLICEP] packed h
    int* flg,                          // [NBG*NCB*16]
    float* __restrict__ dec_outs)      // [(b*PD+p)*H]
{
    __shared__ _Float16 opH[2][RB * LROW];   // [0]=x, [1]=h  (hi parts)
    __shared__ _Float16 opL[2][RB * LROW];   // lo' parts (x2048)
    __shared__ float red0[64 * RSTR], red1[64 * RSTR];
    __shared__ float bi_l[2][GC], bh_l[2][GC];

    const int tid  = threadIdx.x;
    const int L    = blockIdx.x;       // 0..255
    const int xcd  = L & 7;
    const int yy   = L >> 3;
    const int cb   = yy & 15;                          // 0..15
    const int bg   = ((yy >> 4) << 3) | xcd;           // 0..15, group on one XCD
    const int r0   = bg * RB;
    const int c0h  = cb * CBH;
    const int wv   = tid >> 6;         // wave id = col-tile
    const int lane = tid & 63;

    half8 wih_h[NKS], wih_l[NKS], whh_h[NKS], whh_l[NKS];

    // ---- pack weights into B-fragments (per lane: col wv*16+(l&15)) ----
    auto packw = [&](const float* W, half8* wh, half8* wl) {
        int c = wv * 16 + (lane & 15);
        bool valid = (c < GC);
        int g = valid ? c / CBH : 0, j19 = valid ? c - (c / CBH) * CBH : 0;
        const float* wp = W + (size_t)(g * H_ + c0h + j19) * 304;
        int grp = (lane >> 4) * 8;
        #pragma unroll
        for (int ks = 0; ks < NKS; ++ks) {
            half8 vh, vl;
            #pragma unroll
            for (int j = 0; j < 8; ++j) {
                int k = ks * 32 + grp + j;
                float v = (valid && k < 304) ? wp[k] : 0.f;
                _Float16 hi = (_Float16)v;
                float rres = v - (float)hi;
                vh[j] = hi;
                vl[j] = (_Float16)(rres * SC_LO);
            }
            wh[ks] = vh; wl[ks] = vl;
        }
    };

    // ---- GEMM: red[col*RSTR + g*4 ..] = A(16x320).B(320x16), 3-term split ----
    auto gemm = [&](const _Float16* aH, const _Float16* aL,
                    const half8* wh, const half8* wl, float* red) {
        const int base = (lane & 15) * LROW + (lane >> 4) * 8;
        f32x4 a0 = {0.f, 0.f, 0.f, 0.f}, a1 = a0, a2 = a0;
        #pragma unroll
        for (int ks = 0; ks < NKS; ++ks) {
            half8 Ah = *(const half8*)&aH[base + ks * 32];
            half8 Al = *(const half8*)&aL[base + ks * 32];
            a0 = __builtin_amdgcn_mfma_f32_16x16x32_f16(Ah, wh[ks], a0, 0, 0, 0);
            a1 = __builtin_amdgcn_mfma_f32_16x16x32_f16(Ah, wl[ks], a1, 0, 0, 0);
            a2 = __builtin_amdgcn_mfma_f32_16x16x32_f16(Al, wh[ks], a2, 0, 0, 0);
        }
        f32x4 r = a0 + (a1 + a2) * SC_INV;
        // C layout: col = lane&15 (tile wv), rows (lane>>4)*4+i -> one b128
        int rb = (wv * 16 + (lane & 15)) * RSTR + (lane >> 4) * 4;
        *(f32x4*)&red[rb] = r;
    };

    // ---- convert ull (2 f32) -> hi-pair + lo-pair, store to LDS (x path) ----
    auto cvtstore = [&](ull u, int plane, int idx) {
        float a0 = __uint_as_float((unsigned)u);
        float a1 = __uint_as_float((unsigned)(u >> 32));
        _Float16 h0 = (_Float16)a0, h1 = (_Float16)a1;
        float r0f = a0 - (float)h0, r1f = a1 - (float)h1;
        half2v vh; vh.x = h0; vh.y = h1;
        half2v vl; vl.x = (_Float16)(r0f * SC_LO); vl.y = (_Float16)(r1f * SC_LO);
        ((half2v*)&opH[plane][0])[idx] = vh;
        ((half2v*)&opL[plane][0])[idx] = vl;
    };

    packw(eWih, wih_h, wih_l);
    packw(eWhh, whh_h, whh_l);
    if (tid < GC) {
        int g = tid / CBH, j = tid - (tid / CBH) * CBH;
        bi_l[0][tid] = ebih[g * H_ + c0h + j];
        bh_l[0][tid] = ebhh[g * H_ + c0h + j];
        bi_l[1][tid] = dbih[g * H_ + c0h + j];
        bh_l[1][tid] = dbhh[g * H_ + c0h + j];
    }

    // ---- prologue: zero f16 arrays (k-tails 304..319 + pad stay zero) ----
    for (int f = tid; f < RB * LROW; f += 256) {
        ((unsigned*)opH)[f] = 0u;
        ((unsigned*)opL)[f] = 0u;
    }
    __syncthreads();
    // stage x(0)
    {
        const ull* xin = (const ull*)input;
        #pragma unroll
        for (int i = 0; i < 10; ++i) {
            int f = tid + 256 * i;
            if (i < 9 || f < BLK_ULL) {
                int rr = f / HW, q = f - (f / HW) * HW;
                cvtstore(xin[(size_t)(r0 + rr) * T_ * HW + q], 0, rr * LROWU + q);
            }
        }
    }
    __syncthreads();
    gemm(opH[0], opL[0], wih_h, wih_l, red0);      // gi(0)
    // xr <- x(1)
    ull xr[10];
    {
        const ull* xin = (const ull*)input;
        #pragma unroll
        for (int i = 0; i < 10; ++i) {
            int f = tid + 256 * i;
            if (i < 9 || f < BLK_ULL) {
                int rr = f / HW, q = f - (f / HW) * HW;
                xr[i] = xin[((size_t)(r0 + rr) * T_ + 1) * HW + q];
            }
        }
    }

    for (int s = 0; s < NSTEP; ++s) {
        __syncthreads();   // top: opH[0]/opH[1] free (gi of prev iter done)
        const bool enc = (s < T_);
        if (s == T_) packw(dWhh, whh_h, whh_l);    // private regs, race-free

        // ---- stage x(s+1) from xr -> op[0] ----
        if (s + 1 < NSTEP) {
            #pragma unroll
            for (int i = 0; i < 10; ++i) {
                int f = tid + 256 * i;
                if (i < 9 || f < BLK_ULL) {
                    int rr = f / HW, q = f - (f / HW) * HW;
                    cvtstore(xr[i], 0, rr * LROWU + q);
                }
            }
        }
        // ---- issue xr <- x(s+2) (pure prefetch) ----
        if (s + 2 < NSTEP) {
            if (s + 2 < T_) {
                const ull* xin = (const ull*)input;
                #pragma unroll
                for (int i = 0; i < 10; ++i) {
                    int f = tid + 256 * i;
                    if (i < 9 || f < BLK_ULL) {
                        int rr = f / HW, q = f - (f / HW) * HW;
                        xr[i] = xin[((size_t)(r0 + rr) * T_ + (s + 2)) * HW + q];
                    }
                }
            } else {
                const ull* eb = (const ull*)emb;
                int p2 = s + 2 - T_;
                #pragma unroll
                for (int i = 0; i < 10; ++i) {
                    int f = tid + 256 * i;
                    if (i < 9 || f < BLK_ULL) {
                        int rr = f / HW, q = f - (f / HW) * HW;
                        int tok = (p2 == 0) ? 0 : target[(r0 + rr) * P_ + p2];
                        xr[i] = eb[(size_t)tok * HW + q];
                    }
                }
            }
        }
        // ---- consume h(s) slices (per-wave progressive dataflow) ----
        if (s > 0) {
            const unsigned* xb = xbuf
                + ((size_t)(s & 1) * NBG * NCB + (size_t)bg * NCB) * SLICEP;
            for (int k = 0; k < 4; ++k) {
                const int sl = wv + 4 * k;             // producer col-block
                const int* fp = flg + (bg * NCB + sl) * 16;
                while (__hip_atomic_load(fp, __ATOMIC_RELAXED,
                                         __HIP_MEMORY_SCOPE_AGENT) < s)
                    __builtin_amdgcn_s_sleep(1);
                __builtin_amdgcn_sched_barrier(0);
                const unsigned* sp = xb + (size_t)sl * SLICEP;
                #pragma unroll
                for (int p = 0; p < 5; ++p) {
                    int e = lane + 64 * p;
                    if (e < SLICE) {
                        unsigned u = __hip_atomic_load(sp + e, __ATOMIC_RELAXED,
                                                       __HIP_MEMORY_SCOPE_AGENT);
                        int rr = e / CBH, j = e - (e / CBH) * CBH;
                        int idx = rr * LROW + sl * CBH + j;
                        opH[1][idx] = __builtin_bit_cast(_Float16,
                                          (unsigned short)(u & 0xffffu));
                        opL[1][idx] = __builtin_bit_cast(_Float16,
                                          (unsigned short)(u >> 16));
                    }
                }
            }
        }
        __syncthreads();   // mid: op[1] (h) + op[0] (x) ready

        // ---- gh GEMM: h(s) . Whh^T -> red1 ----
        gemm(opH[1], opL[1], whh_h, whh_l, red1);
        __syncthreads();   // red-ready

        // ---- gates -> h(s+1): pack + slice store ----
        unsigned* xdst = xbuf
            + ((size_t)((s + 1) & 1) * NBG * NCB + (size_t)bg * NCB + cb) * SLICEP;
        for (int o = tid; o < RB * CBH; o += 256) {
            int rr = o / CBH, j = o - (o / CBH) * CBH;
            int col = c0h + j;
            int ph = enc ? 0 : 1;
            float Gi[3], Gh[3];
            #pragma unroll
            for (int g = 0; g < 3; ++g) {
                int c = g * CBH + j;
                Gi[g] = red0[c * RSTR + rr] + bi_l[ph][c];
                Gh[g] = red1[c * RSTR + rr] + bh_l[ph][c];
            }
            float rg = 1.f / (1.f + expf(-(Gi[0] + Gh[0])));
            float zg = 1.f / (1.f + expf(-(Gi[1] + Gh[1])));
            float ng = tanhf(Gi[2] + rg * Gh[2]);
            float hv = (float)opH[1][rr * LROW + col]
                     + (float)opL[1][rr * LROW + col] * SC_INV;
            float hnew = (1.f - zg) * ng + zg * hv;
            _Float16 hh = (_Float16)hnew;
            float res = hnew - (float)hh;
            unsigned short hb = __builtin_bit_cast(unsigned short, hh);
            unsigned short lb = __builtin_bit_cast(unsigned short,
                                    (_Float16)(res * SC_LO));
            unsigned pk = ((unsigned)lb << 16) | hb;
            __hip_atomic_store(xdst + o, pk, __ATOMIC_RELAXED,
                               __HIP_MEMORY_SCOPE_AGENT);
            if (!enc)
                dec_outs[((size_t)(r0 + rr) * PD + (s - T_)) * H_ + col] = hnew;
        }
        __syncthreads();   // drain: slice stores ACKed (vmcnt 0); red0 free

        if (s + 1 < NSTEP) {
            if (tid == 0)
                __hip_atomic_store(flg + (bg * NCB + cb) * 16, s + 1,
                                   __ATOMIC_RELAXED, __HIP_MEMORY_SCOPE_AGENT);
            if (s + 1 == T_) packw(dWih, wih_h, wih_l);
            // ---- gi(s+1): x(s+1) . Wih^T -> red0 ----
            gemm(opH[0], opL[0], wih_h, wih_l, red0);
        }
    }
}

// ---------------------------------------------------------------------------
// logits -> softmax -> (softmax_cal, target_cal, asr_outputs)
// ---------------------------------------------------------------------------
__global__ __launch_bounds__(256) void logits_softmax(
    const float* __restrict__ dec_outs,   // [B*PD][H]
    const float* __restrict__ linW,       // [61][304]
    const float* __restrict__ linb,       // [61]
    const int* __restrict__ target,       // [B][P][1]
    float* __restrict__ out)
{
    __shared__ float wsm[H_][64];   // transposed W
    __shared__ float rs[4][H_];
    const int tid = threadIdx.x;
    const int wv = tid >> 6, l = tid & 63;

    for (int f = tid; f < H_ * 64; f += 256) {
        int k = f >> 6, ll = f & 63;
        wsm[k][ll] = (ll < D_) ? linW[(size_t)ll * H_ + k] : 0.f;
    }
    const int r = blockIdx.x * 4 + wv;
    const float* rowp = dec_outs + (size_t)r * H_;
    for (int k = l; k < H_; k += 64) rs[wv][k] = rowp[k];
    __syncthreads();

    float acc = -1e30f;
    if (l < D_) {
        acc = linb[l];
        #pragma unroll 4
        for (int k = 0; k < H_; ++k) acc += rs[wv][k] * wsm[k][l];
    }
    float m = acc;
    for (int off = 32; off; off >>= 1) m = fmaxf(m, __shfl_xor(m, off));
    float e = (l < D_) ? expf(acc - m) : 0.f;
    float s = e;
    for (int off = 32; off; off >>= 1) s += __shfl_xor(s, off);
    float av = acc; int ai = l;
    for (int off = 32; off; off >>= 1) {
        float ov = __shfl_xor(av, off);
        int oi = __shfl_xor(ai, off);
        if (ov > av || (ov == av && oi < ai)) { av = ov; ai = oi; }
    }
    const int b = r / PD, p = r - (r / PD) * PD;
    const size_t OFF1 = (size_t)B_ * PD * D_;
    const size_t OFF2 = OFF1 + (size_t)B_ * PD;
    if (l < D_)        out[(size_t)r * D_ + l] = e / s;
    else if (l == D_)  out[OFF1 + r] = (float)target[b * P_ + p + 1];
    else if (l == D_ + 1) out[OFF2 + r] = (float)ai;
}

// ---------------------------------------------------------------------------
extern "C" void kernel_launch(void* const* d_in, const int* in_sizes, int n_in,
                              void* d_out, int out_size, void* d_ws, size_t ws_size,
                              hipStream_t stream)
{
    const float* input  = (const float*)d_in[0];
    const int*   target = (const int*)d_in[1];
    const float* eWih = (const float*)d_in[3];
    const float* eWhh = (const float*)d_in[4];
    const float* ebih = (const float*)d_in[5];
    const float* ebhh = (const float*)d_in[6];
    const float* emb  = (const float*)d_in[7];
    const float* dWih = (const float*)d_in[8];
    const float* dWhh = (const float*)d_in[9];
    const float* dbih = (const float*)d_in[10];
    const float* dbhh = (const float*)d_in[11];
    const float* linW = (const float*)d_in[12];
    const float* linb = (const float*)d_in[13];
    float* out = (float*)d_out;

    int*      flg      = (int*)d_ws;                       // 16*16*16 ints
    unsigned* xbuf     = (unsigned*)d_ws + NBG * NCB * 16; // 2*16*16*320 u32
    float*    dec_outs = (float*)((unsigned*)xbuf + 2 * NBG * NCB * SLICEP);

    (void)hipMemsetAsync(flg, 0, NBG * NCB * 16 * sizeof(int), stream);

    gru_persist<<<dim3(256), 256, 0, stream>>>(
        input, target, emb,
        eWih, eWhh, ebih, ebhh,
        dWih, dWhh, dbih, dbhh,
        xbuf, flg, dec_outs);

    logits_softmax<<<dim3(B_ * PD / 4), 256, 0, stream>>>(
        dec_outs, linW, linb, target, out);
}

// Round 11
// 2388.481 us; speedup vs baseline: 2.3323x; 2.3323x over previous
//
#include <hip/hip_runtime.h>
#include <math.h>

#define B_   256
#define E_   304
#define H_   304
#define T_   512
#define P_   68
#define PD   67      // decoder output positions
#define D_   61
#define NCB  16      // col-blocks per batch group
#define NBG  16      // batch groups
#define RB   16      // rows (batch) per block -- full MFMA M dim
#define CBH  19      // h-cols per block
#define GC   57      // gate-cols per block (3*19)
#define NSTEP (T_ + PD)
#define HW   152     // ull words per f32 row (304 floats)
#define BLK_ULL (RB * HW)   // 2432
#define LROW 328     // padded f16 row length (K 320 + pad)
#define LROWU 164    // u32 (f16-pair) words per row
#define NKS  10      // K-steps of 32 (K padded 304->320)
#define RSTR 20      // red[] row stride: col*80B + g*16B -> 16B-aligned b128
#define SC_LO 2048.0f
#define SC_INV 4.8828125e-4f   // 2^-11

typedef unsigned long long ull;
typedef _Float16 half8 __attribute__((ext_vector_type(8)));
typedef _Float16 half2v __attribute__((ext_vector_type(2)));
typedef float f32x4 __attribute__((ext_vector_type(4)));

// ---------------------------------------------------------------------------
// Persistent GRU via split-f16 MFMA. Grid 256 blocks, 256 thr, 1 block/CU.
// XCD-local groups (L%8 swizzle). Block (cb,bg): rows r0=bg*16..+15, h-cols
// c0h=cb*19..+18. h exchanged as f32 in double-buffered hbuf (R9-proven bulk
// coalesced path). Sync protocol (R11 change): per-producer FLAG STORES (16
// distinct cachelines, no RMW serialization); consumer wave 0 polls all 16
// flags in parallel (lanes 0..15) and exits on __all(flag >= s+1).
// Causality: drain-__syncthreads waits vmcnt(0) per wave before s_barrier,
// so all h stores are ACKed before tid0's flag store issues.
// Per iter s: top-sync | issue h loads | stage x(s+1) | cvt h | prefetch
// x(s+2) | mid-sync | gh MFMA -> red1 | red-sync | gates -> h(s+1) store
// (+dec_outs) | drain-sync | tid0 flag=s+1 | gi(s+1) -> red0 (hides skew) |
// wave0 parallel flag poll.
// ---------------------------------------------------------------------------
__global__ __launch_bounds__(256, 1) void gru_persist(
    const float* __restrict__ input,   // [B][T][E]
    const int*   __restrict__ target,  // [B][P]
    const float* __restrict__ emb,     // [D][E]
    const float* __restrict__ eWih, const float* __restrict__ eWhh,
    const float* __restrict__ ebih, const float* __restrict__ ebhh,
    const float* __restrict__ dWih, const float* __restrict__ dWhh,
    const float* __restrict__ dbih, const float* __restrict__ dbhh,
    float* hbuf,                       // [2][B*H]
    float* __restrict__ dec_outs,      // [(b*PD+p)*H]
    int* flg)                          // [NBG*NCB*16]
{
    __shared__ _Float16 opH[2][RB * LROW];   // [0]=x, [1]=h  (hi parts)
    __shared__ _Float16 opL[2][RB * LROW];   // lo' parts (x2048)
    __shared__ float red0[64 * RSTR], red1[64 * RSTR];
    __shared__ float bi_l[2][GC], bh_l[2][GC];

    const int tid  = threadIdx.x;
    const int L    = blockIdx.x;       // 0..255
    const int xcd  = L & 7;
    const int yy   = L >> 3;
    const int cb   = yy & 15;                          // 0..15
    const int bg   = ((yy >> 4) << 3) | xcd;           // 0..15, group on one XCD
    const int r0   = bg * RB;
    const int c0h  = cb * CBH;
    const int wv   = tid >> 6;         // wave id = col-tile
    const int lane = tid & 63;

    half8 wih_h[NKS], wih_l[NKS], whh_h[NKS], whh_l[NKS];

    // ---- pack weights into B-fragments (per lane: col wv*16+(l&15)) ----
    auto packw = [&](const float* W, half8* wh, half8* wl) {
        int c = wv * 16 + (lane & 15);
        bool valid = (c < GC);
        int g = valid ? c / CBH : 0, j19 = valid ? c - (c / CBH) * CBH : 0;
        const float* wp = W + (size_t)(g * H_ + c0h + j19) * 304;
        int grp = (lane >> 4) * 8;
        #pragma unroll
        for (int ks = 0; ks < NKS; ++ks) {
            half8 vh, vl;
            #pragma unroll
            for (int j = 0; j < 8; ++j) {
                int k = ks * 32 + grp + j;
                float v = (valid && k < 304) ? wp[k] : 0.f;
                _Float16 hi = (_Float16)v;
                float rres = v - (float)hi;
                vh[j] = hi;
                vl[j] = (_Float16)(rres * SC_LO);
            }
            wh[ks] = vh; wl[ks] = vl;
        }
    };

    // ---- GEMM: red[col*RSTR..] = A(16x320) . B(320x16), 3-term split ----
    auto gemm = [&](const _Float16* aH, const _Float16* aL,
                    const half8* wh, const half8* wl, float* red) {
        const int base = (lane & 15) * LROW + (lane >> 4) * 8;
        f32x4 a0 = {0.f, 0.f, 0.f, 0.f}, a1 = a0, a2 = a0;
        #pragma unroll
        for (int ks = 0; ks < NKS; ++ks) {
            half8 Ah = *(const half8*)&aH[base + ks * 32];
            half8 Al = *(const half8*)&aL[base + ks * 32];
            a0 = __builtin_amdgcn_mfma_f32_16x16x32_f16(Ah, wh[ks], a0, 0, 0, 0);
            a1 = __builtin_amdgcn_mfma_f32_16x16x32_f16(Ah, wl[ks], a1, 0, 0, 0);
            a2 = __builtin_amdgcn_mfma_f32_16x16x32_f16(Al, wh[ks], a2, 0, 0, 0);
        }
        f32x4 r = a0 + (a1 + a2) * SC_INV;
        // C layout: col = lane&15 (tile wv), rows (lane>>4)*4+i -> one b128
        int rb = (wv * 16 + (lane & 15)) * RSTR + (lane >> 4) * 4;
        *(f32x4*)&red[rb] = r;
    };

    // ---- convert ull (2 f32) -> hi-pair + lo-pair, store to LDS ----
    auto cvtstore = [&](ull u, int plane, int idx) {
        float a0 = __uint_as_float((unsigned)u);
        float a1 = __uint_as_float((unsigned)(u >> 32));
        _Float16 h0 = (_Float16)a0, h1 = (_Float16)a1;
        float r0f = a0 - (float)h0, r1f = a1 - (float)h1;
        half2v vh; vh.x = h0; vh.y = h1;
        half2v vl; vl.x = (_Float16)(r0f * SC_LO); vl.y = (_Float16)(r1f * SC_LO);
        ((half2v*)&opH[plane][0])[idx] = vh;
        ((half2v*)&opL[plane][0])[idx] = vl;
    };

    packw(eWih, wih_h, wih_l);
    packw(eWhh, whh_h, whh_l);
    if (tid < GC) {
        int g = tid / CBH, j = tid - (tid / CBH) * CBH;
        bi_l[0][tid] = ebih[g * H_ + c0h + j];
        bh_l[0][tid] = ebhh[g * H_ + c0h + j];
        bi_l[1][tid] = dbih[g * H_ + c0h + j];
        bh_l[1][tid] = dbhh[g * H_ + c0h + j];
    }

    // ---- prologue: zero f16 arrays (k-tails 304..319 + pad stay zero) ----
    for (int f = tid; f < RB * LROW; f += 256) {
        ((unsigned*)opH)[f] = 0u;
        ((unsigned*)opL)[f] = 0u;
    }
    __syncthreads();
    // stage x(0)
    {
        const ull* xin = (const ull*)input;
        #pragma unroll
        for (int i = 0; i < 10; ++i) {
            int f = tid + 256 * i;
            if (i < 9 || f < BLK_ULL) {
                int rr = f / HW, q = f - (f / HW) * HW;
                cvtstore(xin[(size_t)(r0 + rr) * T_ * HW + q], 0, rr * LROWU + q);
            }
        }
    }
    __syncthreads();
    gemm(opH[0], opL[0], wih_h, wih_l, red0);      // gi(0)
    // xr <- x(1)
    ull xr[10];
    {
        const ull* xin = (const ull*)input;
        #pragma unroll
        for (int i = 0; i < 10; ++i) {
            int f = tid + 256 * i;
            if (i < 9 || f < BLK_ULL) {
                int rr = f / HW, q = f - (f / HW) * HW;
                xr[i] = xin[((size_t)(r0 + rr) * T_ + 1) * HW + q];
            }
        }
    }

    for (int s = 0; s < NSTEP; ++s) {
        __syncthreads();   // top: wave0 exited flag poll; red0(gi s) ready
        const bool enc = (s < T_);
        if (s == T_) packw(dWhh, whh_h, whh_l);    // private regs, race-free

        // ---- issue h(s) loads FIRST (MALL latency hidden by x staging) ----
        ull hreg[10];
        if (s > 0) {
            const ull* hsrc = (const ull*)(hbuf + (size_t)(s & 1) * (B_ * H_))
                              + (size_t)r0 * HW;
            #pragma unroll
            for (int i = 0; i < 10; ++i) {
                int f = tid + 256 * i;
                if (i < 9 || f < BLK_ULL)
                    hreg[i] = __hip_atomic_load(hsrc + f, __ATOMIC_RELAXED,
                                                __HIP_MEMORY_SCOPE_AGENT);
            }
        }
        // ---- stage x(s+1) from xr -> op[0] (independent VALU/LDS work) ----
        if (s + 1 < NSTEP) {
            #pragma unroll
            for (int i = 0; i < 10; ++i) {
                int f = tid + 256 * i;
                if (i < 9 || f < BLK_ULL) {
                    int rr = f / HW, q = f - (f / HW) * HW;
                    cvtstore(xr[i], 0, rr * LROWU + q);
                }
            }
        }
        // ---- convert h -> op[1] ----
        if (s > 0) {
            #pragma unroll
            for (int i = 0; i < 10; ++i) {
                int f = tid + 256 * i;
                if (i < 9 || f < BLK_ULL) {
                    int rr = f / HW, q = f - (f / HW) * HW;
                    cvtstore(hreg[i], 1, rr * LROWU + q);
                }
            }
        }
        // ---- issue xr <- x(s+2) (pure prefetch) ----
        if (s + 2 < NSTEP) {
            if (s + 2 < T_) {
                const ull* xin = (const ull*)input;
                #pragma unroll
                for (int i = 0; i < 10; ++i) {
                    int f = tid + 256 * i;
                    if (i < 9 || f < BLK_ULL) {
                        int rr = f / HW, q = f - (f / HW) * HW;
                        xr[i] = xin[((size_t)(r0 + rr) * T_ + (s + 2)) * HW + q];
                    }
                }
            } else {
                const ull* eb = (const ull*)emb;
                int p2 = s + 2 - T_;
                #pragma unroll
                for (int i = 0; i < 10; ++i) {
                    int f = tid + 256 * i;
                    if (i < 9 || f < BLK_ULL) {
                        int rr = f / HW, q = f - (f / HW) * HW;
                        int tok = (p2 == 0) ? 0 : target[(r0 + rr) * P_ + p2];
                        xr[i] = eb[(size_t)tok * HW + q];
                    }
                }
            }
        }
        __syncthreads();   // mid: op[1] (h) ready

        // ---- gh GEMM: h(s) . Whh^T -> red1 ----
        gemm(opH[1], opL[1], whh_h, whh_l, red1);
        __syncthreads();   // red-ready

        // ---- gates -> h(s+1) ----
        float* hdst = hbuf + (size_t)((s + 1) & 1) * (B_ * H_);
        for (int o = tid; o < RB * CBH; o += 256) {
            int rr = o / CBH, j = o - (o / CBH) * CBH;
            int col = c0h + j;
            int ph = enc ? 0 : 1;
            float Gi[3], Gh[3];
            #pragma unroll
            for (int g = 0; g < 3; ++g) {
                int c = g * CBH + j;
                Gi[g] = red0[c * RSTR + rr] + bi_l[ph][c];
                Gh[g] = red1[c * RSTR + rr] + bh_l[ph][c];
            }
            float rg = 1.f / (1.f + expf(-(Gi[0] + Gh[0])));
            float zg = 1.f / (1.f + expf(-(Gi[1] + Gh[1])));
            float ng = tanhf(Gi[2] + rg * Gh[2]);
            float hv = (float)opH[1][rr * LROW + col]
                     + (float)opL[1][rr * LROW + col] * SC_INV;
            float hnew = (1.f - zg) * ng + zg * hv;
            __hip_atomic_store(&hdst[(size_t)(r0 + rr) * H_ + col], hnew,
                               __ATOMIC_RELAXED, __HIP_MEMORY_SCOPE_AGENT);
            if (!enc)
                dec_outs[((size_t)(r0 + rr) * PD + (s - T_)) * H_ + col] = hnew;
        }
        __syncthreads();   // drain: h stores ACKed (vmcnt 0 per wave); red0 free

        if (s + 1 < NSTEP) {
            // per-producer flag store: no RMW, no serialization
            if (tid == 0)
                __hip_atomic_store(flg + (bg * NCB + cb) * 16, s + 1,
                                   __ATOMIC_RELAXED, __HIP_MEMORY_SCOPE_AGENT);
            if (s + 1 == T_) packw(dWih, wih_h, wih_l);
            // ---- gi(s+1): x(s+1) . Wih^T -> red0 (overlaps peer skew) ----
            gemm(opH[0], opL[0], wih_h, wih_l, red0);
            // ---- wave 0: parallel poll of all 16 producer flags ----
            if (wv == 0) {
                const int tgt = s + 1;
                const int* fp = flg + (bg * NCB + (lane & 15)) * 16;
                for (;;) {
                    int f = (lane < NCB)
                        ? __hip_atomic_load(fp, __ATOMIC_RELAXED,
                                            __HIP_MEMORY_SCOPE_AGENT)
                        : tgt;
                    if (__all(f >= tgt)) break;
                    __builtin_amdgcn_s_sleep(1);
                }
            }
        }
    }
}

// ---------------------------------------------------------------------------
// logits -> softmax -> (softmax_cal, target_cal, asr_outputs)
// ---------------------------------------------------------------------------
__global__ __launch_bounds__(256) void logits_softmax(
    const float* __restrict__ dec_outs,   // [B*PD][H]
    const float* __restrict__ linW,       // [61][304]
    const float* __restrict__ linb,       // [61]
    const int* __restrict__ target,       // [B][P][1]
    float* __restrict__ out)
{
    __shared__ float wsm[H_][64];   // transposed W
    __shared__ float rs[4][H_];
    const int tid = threadIdx.x;
    const int wv = tid >> 6, l = tid & 63;

    for (int f = tid; f < H_ * 64; f += 256) {
        int k = f >> 6, ll = f & 63;
        wsm[k][ll] = (ll < D_) ? linW[(size_t)ll * H_ + k] : 0.f;
    }
    const int r = blockIdx.x * 4 + wv;
    const float* rowp = dec_outs + (size_t)r * H_;
    for (int k = l; k < H_; k += 64) rs[wv][k] = rowp[k];
    __syncthreads();

    float acc = -1e30f;
    if (l < D_) {
        acc = linb[l];
        #pragma unroll 4
        for (int k = 0; k < H_; ++k) acc += rs[wv][k] * wsm[k][l];
    }
    float m = acc;
    for (int off = 32; off; off >>= 1) m = fmaxf(m, __shfl_xor(m, off));
    float e = (l < D_) ? expf(acc - m) : 0.f;
    float s = e;
    for (int off = 32; off; off >>= 1) s += __shfl_xor(s, off);
    float av = acc; int ai = l;
    for (int off = 32; off; off >>= 1) {
        float ov = __shfl_xor(av, off);
        int oi = __shfl_xor(ai, off);
        if (ov > av || (ov == av && oi < ai)) { av = ov; ai = oi; }
    }
    const int b = r / PD, p = r - (r / PD) * PD;
    const size_t OFF1 = (size_t)B_ * PD * D_;
    const size_t OFF2 = OFF1 + (size_t)B_ * PD;
    if (l < D_)        out[(size_t)r * D_ + l] = e / s;
    else if (l == D_)  out[OFF1 + r] = (float)target[b * P_ + p + 1];
    else if (l == D_ + 1) out[OFF2 + r] = (float)ai;
}

// ---------------------------------------------------------------------------
extern "C" void kernel_launch(void* const* d_in, const int* in_sizes, int n_in,
                              void* d_out, int out_size, void* d_ws, size_t ws_size,
                              hipStream_t stream)
{
    const float* input  = (const float*)d_in[0];
    const int*   target = (const int*)d_in[1];
    const float* eWih = (const float*)d_in[3];
    const float* eWhh = (const float*)d_in[4];
    const float* ebih = (const float*)d_in[5];
    const float* ebhh = (const float*)d_in[6];
    const float* emb  = (const float*)d_in[7];
    const float* dWih = (const float*)d_in[8];
    const float* dWhh = (const float*)d_in[9];
    const float* dbih = (const float*)d_in[10];
    const float* dbhh = (const float*)d_in[11];
    const float* linW = (const float*)d_in[12];
    const float* linb = (const float*)d_in[13];
    float* out = (float*)d_out;

    int*   flg      = (int*)d_ws;                    // NBG*NCB*16 ints (16 KB)
    float* hbuf     = (float*)d_ws + NBG * NCB * 16; // 2 * B*H
    float* dec_outs = hbuf + 2 * (size_t)B_ * H_;    // B*PD*H

    (void)hipMemsetAsync(flg, 0, NBG * NCB * 16 * sizeof(int), stream);

    gru_persist<<<dim3(256), 256, 0, stream>>>(
        input, target, emb,
        eWih, eWhh, ebih, ebhh,
        dWih, dWhh, dbih, dbhh,
        hbuf, dec_outs, flg);

    logits_softmax<<<dim3(B_ * PD / 4), 256, 0, stream>>>(
        dec_outs, linW, linb, target, out);
}